// Round 8
// baseline (383.354 us; speedup 1.0000x reference)
//
#include <hip/hip_runtime.h>

namespace {

constexpr int B = 128, N = 2048, E = 32768;
constexpr int LOG2N = 11, LOG2E = 15;

// ws layout (bytes)
constexpr size_t OFF_P1 = 0;                          // layer1 partials: B*2*6*N*4 = 12 MB
constexpr size_t OFF_O2 = 12u * 1024 * 1024;          // layer2 node partials: 24 KB

__device__ __forceinline__ float hw_cos(float s)  { float d; asm("v_cos_f32 %0, %1" : "=v"(d) : "v"(s)); return d; }
__device__ __forceinline__ float hw_exp2(float s) { float d; asm("v_exp_f32 %0, %1" : "=v"(d) : "v"(s)); return d; }

// R12 edge-parallel layer, no sort. Two fixes over R7 (which ran 137us at
// 9% VALUBusy, LDS-pipe-stalled):
//  1) NATIVE FP ATOMICS: atomicAdd(float*) on LDS lowers to a CAS retry
//     loop (ds_read+ds_cmpst+divergent branch) without unsafe-fp-atomics.
//     unsafeAtomicAdd emits hardware ds_add_f32. ~98K CAS atomics/block was
//     the dominant stall.
//  2) PLANAR lh: float4-strided gathers start at bank (idx*4)&31 -> only 8
//     bank-groups -> ~8-way conflict per gather. Four float[N] planes put
//     ds_read_b32 at bank idx&31 -> full spread, ~2-way (free).
// MODE 0: lh = x[b]; writes all-node partials to part1[b][half][6][N].
// MODE 1: lh = h1 reconstructed from x + part1 (both halves); writes only
//         src/dst node partials to out2.
template <int MODE>
__global__ __launch_bounds__(1024, 4) void layerE_kernel(
    const float4* __restrict__ x, const int* __restrict__ edge_index,
    const float* __restrict__ edge_time, const float* __restrict__ timestamp,
    const float* __restrict__ part1, float* __restrict__ part1out,
    float* __restrict__ out2,
    const int* __restrict__ src_index, const int* __restrict__ dst_index,
    const float* __restrict__ tw, const float* __restrict__ tb,
    const float* __restrict__ Wq, const float* __restrict__ Wk,
    const float* __restrict__ Wv, const float* __restrict__ WoP,
    const float* __restrict__ boP) {
  __shared__ float lhx[N], lhy[N], lhz[N], lhw[N];  // 32 KB planar
  __shared__ float accS[6 * N];                     // 48 KB
  int blk = blockIdx.x, b = blk >> 1, half = blk & 1, t = threadIdx.x;

  constexpr float INV2PI = 0.15915494309189535f;
  constexpr float QSCALE = 0.70710678118654752f * 1.4426950408889634f;  // rs2*log2e
  float twf2[4], tbf2[4], wqc[16], wkh[16], wkp[16], wvh[16], wvp[16];
#pragma unroll
  for (int j = 0; j < 4; j++) { twf2[j] = tw[j] * INV2PI; tbf2[j] = tb[j] * INV2PI; }
#pragma unroll
  for (int j = 0; j < 16; j++) wqc[j] = Wq[j] * QSCALE;
#pragma unroll
  for (int j = 0; j < 16; j++) { wkh[j] = Wk[j]; wkp[j] = Wk[16 + j]; }
#pragma unroll
  for (int j = 0; j < 16; j++) { wvh[j] = Wv[j]; wvp[j] = Wv[16 + j]; }

  // ---- prologue: fill lh planes ----
  if constexpr (MODE == 0) {
    const float4* hb = x + (((size_t)b) << LOG2N);
#pragma unroll
    for (int nn = 0; nn < 2; ++nn) {
      int n = t + nn * 1024;
      float4 v = hb[n];
      lhx[n] = v.x; lhy[n] = v.y; lhz[n] = v.z; lhw[n] = v.w;
    }
  } else {
    const float* p1 = part1 + ((size_t)(b * 2)) * 6 * N;
#pragma unroll
    for (int nn = 0; nn < 2; ++nn) {
      int n = t + nn * 1024;
      float sarr[6];
#pragma unroll
      for (int j = 0; j < 6; j++) sarr[j] = p1[j * N + n] + p1[6 * N + j * N + n];
      float den0 = (sarr[0] == 0.f) ? 1.f : sarr[0];
      float den1 = (sarr[1] == 0.f) ? 1.f : sarr[1];
      float at0 = sarr[2] / den0, at1 = sarr[3] / den0;
      float at2 = sarr[4] / den1, at3 = sarr[5] / den1;
      float4 xb = x[(((size_t)b) << LOG2N) + n];
      float o0 = boP[0] + at0 * WoP[0] + at1 * WoP[4] + at2 * WoP[8]  + at3 * WoP[12];
      float o1 = boP[1] + at0 * WoP[1] + at1 * WoP[5] + at2 * WoP[9]  + at3 * WoP[13];
      float o2 = boP[2] + at0 * WoP[2] + at1 * WoP[6] + at2 * WoP[10] + at3 * WoP[14];
      float o3 = boP[3] + at0 * WoP[3] + at1 * WoP[7] + at2 * WoP[11] + at3 * WoP[15];
      lhx[n] = fmaxf(xb.x + o0, 0.f);
      lhy[n] = fmaxf(xb.y + o1, 0.f);
      lhz[n] = fmaxf(xb.z + o2, 0.f);
      lhw[n] = fmaxf(xb.w + o3, 0.f);
    }
  }
  // zero accumulators (12288 floats = 3072 float4)
  {
    float4* a4 = (float4*)accS;
    float4 z = make_float4(0.f, 0.f, 0.f, 0.f);
    a4[t] = z; a4[t + 1024] = z; a4[t + 2048] = z;
  }
  __syncthreads();

  // ---- edge loop: 16 coalesced windows, depth-1 prefetch ----
  const int* __restrict__ srcp = edge_index + (((size_t)(2 * b)) << LOG2E) + half * (E / 2);
  const int* __restrict__ dstp = edge_index + (((size_t)(2 * b + 1)) << LOG2E) + half * (E / 2);
  const float* __restrict__ etp = edge_time + (((size_t)b) << LOG2E) + half * (E / 2);
  float ts = timestamp[b];

  int sC = srcp[t], dC = dstp[t];
  float eC = etp[t];
#pragma unroll
  for (int k = 0; k < 16; ++k) {
    int sN = 0, dN = 0; float eN = 0.f;
    if (k < 15) {
      int idx = (k + 1) * 1024 + t;
      sN = srcp[idx]; dN = dstp[idx]; eN = etp[idx];
    }
    float hsx = lhx[sC], hsy = lhy[sC], hsz = lhz[sC], hsw = lhw[sC];
    float hdx = lhx[dC], hdy = lhy[dC], hdz = lhz[dC], hdw = lhw[dC];
    float dt = ts - eC;

    float ph0 = hw_cos(dt * twf2[0] + tbf2[0]);
    float ph1 = hw_cos(dt * twf2[1] + tbf2[1]);
    float ph2 = hw_cos(dt * twf2[2] + tbf2[2]);
    float ph3 = hw_cos(dt * twf2[3] + tbf2[3]);

    float q0 = hdx * wqc[0] + hdy * wqc[4] + hdz * wqc[8]  + hdw * wqc[12];
    float q1 = hdx * wqc[1] + hdy * wqc[5] + hdz * wqc[9]  + hdw * wqc[13];
    float q2 = hdx * wqc[2] + hdy * wqc[6] + hdz * wqc[10] + hdw * wqc[14];
    float q3 = hdx * wqc[3] + hdy * wqc[7] + hdz * wqc[11] + hdw * wqc[15];

    float k0 = hsx * wkh[0] + hsy * wkh[4] + hsz * wkh[8]  + hsw * wkh[12]
             + ph0 * wkp[0] + ph1 * wkp[4] + ph2 * wkp[8]  + ph3 * wkp[12];
    float k1 = hsx * wkh[1] + hsy * wkh[5] + hsz * wkh[9]  + hsw * wkh[13]
             + ph0 * wkp[1] + ph1 * wkp[5] + ph2 * wkp[9]  + ph3 * wkp[13];
    float k2 = hsx * wkh[2] + hsy * wkh[6] + hsz * wkh[10] + hsw * wkh[14]
             + ph0 * wkp[2] + ph1 * wkp[6] + ph2 * wkp[10] + ph3 * wkp[14];
    float k3 = hsx * wkh[3] + hsy * wkh[7] + hsz * wkh[11] + hsw * wkh[15]
             + ph0 * wkp[3] + ph1 * wkp[7] + ph2 * wkp[11] + ph3 * wkp[15];

    float p0 = hw_exp2(q0 * k0 + q1 * k1);
    float p1 = hw_exp2(q2 * k2 + q3 * k3);

    float v0 = hsx * wvh[0] + hsy * wvh[4] + hsz * wvh[8]  + hsw * wvh[12]
             + ph0 * wvp[0] + ph1 * wvp[4] + ph2 * wvp[8]  + ph3 * wvp[12];
    float v1 = hsx * wvh[1] + hsy * wvh[5] + hsz * wvh[9]  + hsw * wvh[13]
             + ph0 * wvp[1] + ph1 * wvp[5] + ph2 * wvp[9]  + ph3 * wvp[13];
    float v2 = hsx * wvh[2] + hsy * wvh[6] + hsz * wvh[10] + hsw * wvh[14]
             + ph0 * wvp[2] + ph1 * wvp[6] + ph2 * wvp[10] + ph3 * wvp[14];
    float v3 = hsx * wvh[3] + hsy * wvh[7] + hsz * wvh[11] + hsw * wvh[15]
             + ph0 * wvp[3] + ph1 * wvp[7] + ph2 * wvp[11] + ph3 * wvp[15];

    unsafeAtomicAdd(&accS[0 * N + dC], p0);
    unsafeAtomicAdd(&accS[1 * N + dC], p1);
    unsafeAtomicAdd(&accS[2 * N + dC], p0 * v0);
    unsafeAtomicAdd(&accS[3 * N + dC], p0 * v1);
    unsafeAtomicAdd(&accS[4 * N + dC], p1 * v2);
    unsafeAtomicAdd(&accS[5 * N + dC], p1 * v3);

    sC = sN; dC = dN; eC = eN;
  }

  __syncthreads();

  // ---- epilogue ----
  if constexpr (MODE == 0) {
    float4* po = (float4*)(part1out + ((size_t)(b * 2 + half)) * 6 * N);
    const float4* a4 = (const float4*)accS;
    po[t] = a4[t]; po[t + 1024] = a4[t + 1024]; po[t + 2048] = a4[t + 2048];
  } else {
    if (t < 12) {
      int slot = t / 6, j = t % 6;
      int node = (slot == 0) ? src_index[b] : dst_index[b];
      out2[(((size_t)(b * 2 + half)) * 2 + slot) * 6 + j] = accS[j * N + node];
    }
  }
}

// Final: reconstruct h1 (x + part1, layer0 Wo/bo) and h2 (h1 + out2, layer1
// Wo/bo) for just the src/dst nodes, then the linear head. (R6-validated.)
__global__ void final_kernel(const float4* __restrict__ x,
                             const float* __restrict__ part1,
                             const float* __restrict__ out2,
                             const int* __restrict__ src_index, const int* __restrict__ dst_index,
                             const float* __restrict__ timestamp,
                             const float* __restrict__ tw, const float* __restrict__ tb,
                             const float* __restrict__ Wo, const float* __restrict__ bo,
                             const float* __restrict__ W_lin, const float* __restrict__ b_lin,
                             float* __restrict__ out) {
  int b = threadIdx.x;
  if (b >= B) return;
  int nodes[2] = { src_index[b], dst_index[b] };
  float ts = timestamp[b];
  const float* p1 = part1 + ((size_t)(b * 2)) * 6 * N;
  float h2v[2][4];
#pragma unroll
  for (int slot = 0; slot < 2; ++slot) {
    int n = nodes[slot];
    float sarr[6];
#pragma unroll
    for (int j = 0; j < 6; j++) sarr[j] = p1[j * N + n] + p1[6 * N + j * N + n];
    float den0 = (sarr[0] == 0.f) ? 1.f : sarr[0];
    float den1 = (sarr[1] == 0.f) ? 1.f : sarr[1];
    float at0 = sarr[2] / den0, at1 = sarr[3] / den0;
    float at2 = sarr[4] / den1, at3 = sarr[5] / den1;
    float4 xb = x[(((size_t)b) << LOG2N) + n];
    float h10 = fmaxf(xb.x + bo[0] + at0 * Wo[0] + at1 * Wo[4] + at2 * Wo[8]  + at3 * Wo[12], 0.f);
    float h11 = fmaxf(xb.y + bo[1] + at0 * Wo[1] + at1 * Wo[5] + at2 * Wo[9]  + at3 * Wo[13], 0.f);
    float h12 = fmaxf(xb.z + bo[2] + at0 * Wo[2] + at1 * Wo[6] + at2 * Wo[10] + at3 * Wo[14], 0.f);
    float h13 = fmaxf(xb.w + bo[3] + at0 * Wo[3] + at1 * Wo[7] + at2 * Wo[11] + at3 * Wo[15], 0.f);
    float t2[6];
#pragma unroll
    for (int j = 0; j < 6; j++)
      t2[j] = out2[(((size_t)(b * 2 + 0)) * 2 + slot) * 6 + j]
            + out2[(((size_t)(b * 2 + 1)) * 2 + slot) * 6 + j];
    float d20 = (t2[0] == 0.f) ? 1.f : t2[0];
    float d21 = (t2[1] == 0.f) ? 1.f : t2[1];
    float b0 = t2[2] / d20, b1 = t2[3] / d20, b2 = t2[4] / d21, b3 = t2[5] / d21;
    const float* Wo1 = Wo + 16; const float* bo1 = bo + 4;
    h2v[slot][0] = fmaxf(h10 + bo1[0] + b0 * Wo1[0] + b1 * Wo1[4] + b2 * Wo1[8]  + b3 * Wo1[12], 0.f);
    h2v[slot][1] = fmaxf(h11 + bo1[1] + b0 * Wo1[1] + b1 * Wo1[5] + b2 * Wo1[9]  + b3 * Wo1[13], 0.f);
    h2v[slot][2] = fmaxf(h12 + bo1[2] + b0 * Wo1[2] + b1 * Wo1[6] + b2 * Wo1[10] + b3 * Wo1[14], 0.f);
    h2v[slot][3] = fmaxf(h13 + bo1[3] + b0 * Wo1[3] + b1 * Wo1[7] + b2 * Wo1[11] + b3 * Wo1[15], 0.f);
  }
  float f[12];
#pragma unroll
  for (int j = 0; j < 4; j++) { f[j] = h2v[0][j]; f[4 + j] = h2v[1][j]; }
#pragma unroll
  for (int j = 0; j < 4; j++) f[8 + j] = __cosf(ts * tw[j] + tb[j]);
#pragma unroll
  for (int c = 0; c < 2; c++) {
    float o = b_lin[c];
#pragma unroll
    for (int j = 0; j < 12; j++) o += f[j] * W_lin[j * 2 + c];
    out[b * 2 + c] = o;
  }
}

}  // namespace

extern "C" void kernel_launch(void* const* d_in, const int* in_sizes, int n_in,
                              void* d_out, int out_size, void* d_ws, size_t ws_size,
                              hipStream_t stream) {
  (void)in_sizes; (void)n_in; (void)out_size; (void)ws_size;
  const float* x         = (const float*)d_in[0];
  const int*   edge_idx  = (const int*)d_in[1];
  const float* edge_time = (const float*)d_in[2];
  const float* timestamp = (const float*)d_in[3];
  const int*   src_index = (const int*)d_in[4];
  const int*   dst_index = (const int*)d_in[5];
  const float* time_w    = (const float*)d_in[6];
  const float* time_b    = (const float*)d_in[7];
  const float* Wq        = (const float*)d_in[8];
  const float* Wk        = (const float*)d_in[9];
  const float* Wv        = (const float*)d_in[10];
  const float* Wo        = (const float*)d_in[11];
  const float* bo        = (const float*)d_in[12];
  const float* W_lin     = (const float*)d_in[13];
  const float* b_lin     = (const float*)d_in[14];

  char* ws = (char*)d_ws;
  float* part1 = (float*)(ws + OFF_P1);
  float* out2  = (float*)(ws + OFF_O2);

  layerE_kernel<0><<<2 * B, 1024, 0, stream>>>(
      (const float4*)x, edge_idx, edge_time, timestamp, nullptr, part1, nullptr,
      src_index, dst_index, time_w, time_b,
      Wq + 0, Wk + 0, Wv + 0, nullptr, nullptr);

  layerE_kernel<1><<<2 * B, 1024, 0, stream>>>(
      (const float4*)x, edge_idx, edge_time, timestamp, part1, nullptr, out2,
      src_index, dst_index, time_w, time_b,
      Wq + 16, Wk + 32, Wv + 32, Wo + 0, bo + 0);

  final_kernel<<<1, 128, 0, stream>>>(
      (const float4*)x, part1, out2, src_index, dst_index, timestamp,
      time_w, time_b, Wo, bo, W_lin, b_lin, (float*)d_out);
}

// Round 9
// 193.219 us; speedup vs baseline: 1.9840x; 1.9840x over previous
//
#include <hip/hip_runtime.h>

namespace {

constexpr int B = 128, N = 2048, E = 32768;
constexpr int LOG2N = 11, LOG2E = 15;
constexpr int QE = E / 4;          // edges per quarter block = 8192
constexpr int LOG2QE = 13;

// ws layout (bytes)
constexpr size_t OFF_H0 = 0;                     // B*N float4 = 4 MB
constexpr size_t OFF_H1 = 4u * 1024 * 1024;      // B*N float4 = 4 MB
constexpr size_t OFF_S8 = 8u * 1024 * 1024;      // B*4 quarters * QE int2 = 32 MB
constexpr size_t OFF_RP = 40u * 1024 * 1024;     // B*4*(N+1) int ~ 4.2 MB
constexpr size_t OFF_PM = 45u * 1024 * 1024;     // degree-sorted node perm: B*N int = 1 MB

// One block per (batch, quarter). Builds a per-quarter CSR of (src, dt)
// records entirely in LDS, then streams it out coalesced. (R3-verbatim.)
__global__ __launch_bounds__(1024) void sort_kernel(const int* __restrict__ edge_index,
                                                    const float* __restrict__ edge_time,
                                                    const float* __restrict__ timestamp,
                                                    int2* __restrict__ sorted8,
                                                    int* __restrict__ row_ptr) {
  __shared__ int  cnt[N];        // 8 KB: counts -> cursors
  __shared__ int  wsum[16];
  __shared__ int2 rec[QE];       // 64 KB: local CSR records
  int blk = blockIdx.x, b = blk >> 2, q = blk & 3, t = threadIdx.x;

  cnt[t] = 0; cnt[t + 1024] = 0;
  __syncthreads();

  const int* src_arr = edge_index + (((size_t)(2 * b)) << LOG2E) + q * QE;
  const int* dst_arr = edge_index + (((size_t)(2 * b + 1)) << LOG2E) + q * QE;
  const float* et    = edge_time + (((size_t)b) << LOG2E) + q * QE;
  float ts = timestamp[b];

  // single-pass edge staging into registers (indices all compile-time)
  int srcv[8], dstv[8]; float dtv[8];
#pragma unroll
  for (int k = 0; k < 8; ++k) {
    int e = t + k * 1024;
    srcv[k] = src_arr[e];
    dstv[k] = dst_arr[e];
    dtv[k]  = ts - et[e];
  }

  // hist
#pragma unroll
  for (int k = 0; k < 8; ++k) atomicAdd(&cnt[dstv[k]], 1);
  __syncthreads();

  // exclusive scan of 2048 counts: wave shuffle + 16-partial scan
  int i0 = 2 * t, i1 = 2 * t + 1;
  int l0 = cnt[i0], l1 = cnt[i1];
  int sum = l0 + l1;
  int lane = t & 63, wid = t >> 6;
  int incl = sum;
#pragma unroll
  for (int d = 1; d < 64; d <<= 1) {
    int v = __shfl_up(incl, d, 64);
    if (lane >= d) incl += v;
  }
  if (lane == 63) wsum[wid] = incl;
  __syncthreads();
  if (t < 16) {
    int v = wsum[t];
    int inc = v;
#pragma unroll
    for (int d = 1; d < 16; d <<= 1) {
      int u = __shfl_up(inc, d, 16);
      if (t >= d) inc += u;
    }
    wsum[t] = inc - v;  // exclusive wave offset
  }
  __syncthreads();
  int run = wsum[wid] + (incl - sum);
  int run2 = run + l0;
  int* rp = row_ptr + (size_t)blk * (N + 1);
  rp[i0] = run;
  rp[i1] = run2;
  if (t == 1023) rp[N] = QE;
  cnt[i0] = run;   // becomes cursor
  cnt[i1] = run2;
  __syncthreads();

  // scatter into LDS CSR straight from registers
#pragma unroll
  for (int k = 0; k < 8; ++k) {
    int pos = atomicAdd(&cnt[dstv[k]], 1);
    rec[pos] = make_int2(srcv[k], __float_as_int(dtv[k]));
  }
  __syncthreads();

  // coalesced stream-out (int4 = 2 records)
  const int4* rec4 = (const int4*)rec;
  int4* out4 = (int4*)(sorted8 + (((size_t)blk) << LOG2QE));
#pragma unroll
  for (int i = t; i < QE / 2; i += 1024) out4[i] = rec4[i];
}

// R13: degree-sort permutation. Per batch: node total degree from row_ptr,
// counting-sort (64 bins) -> perm[rank] = node, rank ascending by degree.
// Layer waves then process degree-homogeneous nodes: wave trip count drops
// from max-of-64-Binomial (~27) to ~within-wave spread (~17).
__global__ __launch_bounds__(256) void perm_kernel(const int* __restrict__ row_ptr,
                                                   int* __restrict__ perm) {
  __shared__ int hist[64];
  __shared__ int base[64];
  int b = blockIdx.x, t = threadIdx.x;
  if (t < 64) hist[t] = 0;
  __syncthreads();
  int deg[8];
#pragma unroll
  for (int k = 0; k < 8; ++k) {
    int n = t + k * 256;
    int d = 0;
#pragma unroll
    for (int q = 0; q < 4; ++q) {
      const int* rp = row_ptr + (size_t)(b * 4 + q) * (N + 1);
      d += rp[n + 1] - rp[n];
    }
    deg[k] = min(d, 63);
    atomicAdd(&hist[deg[k]], 1);
  }
  __syncthreads();
  if (t == 0) {
    int run = 0;
    for (int i = 0; i < 64; ++i) { base[i] = run; run += hist[i]; }
  }
  __syncthreads();
  if (t < 64) hist[t] = 0;   // reuse as per-bin cursor
  __syncthreads();
#pragma unroll
  for (int k = 0; k < 8; ++k) {
    int n = t + k * 256;
    int r = base[deg[k]] + atomicAdd(&hist[deg[k]], 1);
    perm[(size_t)b * N + r] = n;
  }
}

// R3 layer body verbatim; single change: thread's node comes from the
// degree-sorted permutation (wave lanes get similar-degree nodes).
__global__ __launch_bounds__(1024) void layer_kernel(const float4* __restrict__ h_in,
                                                     float4* __restrict__ h_out,
                                                     const int* __restrict__ row_ptr,
                                                     const int2* __restrict__ sorted8,
                                                     const int* __restrict__ perm,
                                                     const float* __restrict__ tw,
                                                     const float* __restrict__ tb,
                                                     const float* __restrict__ Wq,
                                                     const float* __restrict__ Wk,
                                                     const float* __restrict__ Wv,
                                                     const float* __restrict__ Wo,
                                                     const float* __restrict__ bo) {
  __shared__ float4 lh[N];  // 32 KB
  int blk = blockIdx.x, b = blk >> 1, half = blk & 1, t = threadIdx.x;

  const float4* hb = h_in + (((size_t)b) << LOG2N);
  lh[t] = hb[t];
  lh[t + 1024] = hb[t + 1024];

  constexpr float INV2PI = 0.15915494309189535f;
  constexpr float QSCALE = 0.70710678118654752f * 1.4426950408889634f;  // rs2*log2e
  float twf2[4], tbf2[4], wq[16], wkh[16], wkp[16], wvh[16], wvp[16];
#pragma unroll
  for (int j = 0; j < 4; j++) { twf2[j] = tw[j] * INV2PI; tbf2[j] = tb[j] * INV2PI; }
#pragma unroll
  for (int j = 0; j < 16; j++) wq[j] = Wq[j];
#pragma unroll
  for (int j = 0; j < 16; j++) { wkh[j] = Wk[j]; wkp[j] = Wk[16 + j]; }
#pragma unroll
  for (int j = 0; j < 16; j++) { wvh[j] = Wv[j]; wvp[j] = Wv[16 + j]; }
  __syncthreads();

  int n = perm[(size_t)b * N + half * 1024 + t];   // degree-sorted assignment
  {
    float4 hn = lh[n];
    float q0 = (hn.x * wq[0] + hn.y * wq[4] + hn.z * wq[8]  + hn.w * wq[12]) * QSCALE;
    float q1 = (hn.x * wq[1] + hn.y * wq[5] + hn.z * wq[9]  + hn.w * wq[13]) * QSCALE;
    float q2 = (hn.x * wq[2] + hn.y * wq[6] + hn.z * wq[10] + hn.w * wq[14]) * QSCALE;
    float q3 = (hn.x * wq[3] + hn.y * wq[7] + hn.z * wq[11] + hn.w * wq[15]) * QSCALE;
#pragma unroll
    for (int i = 0; i < 4; i++) {
      wq[i]      = q0 * wkh[i * 4 + 0] + q1 * wkh[i * 4 + 1];  // wH0
      wq[4 + i]  = q2 * wkh[i * 4 + 2] + q3 * wkh[i * 4 + 3];  // wH1
      wq[8 + i]  = q0 * wkp[i * 4 + 0] + q1 * wkp[i * 4 + 1];  // wA
      wq[12 + i] = q2 * wkp[i * 4 + 2] + q3 * wkp[i * 4 + 3];  // wB
    }
  }

  // flattened cursor over the 4 quarter CSR segments (absolute record index)
  int stage = 0, addr, rem, total;
  int b1, b2, b3, c1, c2, c3;
  {
    const int* rp0 = row_ptr + (size_t)(b * 4 + 0) * (N + 1);
    const int* rp1 = row_ptr + (size_t)(b * 4 + 1) * (N + 1);
    const int* rp2 = row_ptr + (size_t)(b * 4 + 2) * (N + 1);
    const int* rp3 = row_ptr + (size_t)(b * 4 + 3) * (N + 1);
    int s0 = rp0[n], e0 = rp0[n + 1];
    int s1 = rp1[n], e1 = rp1[n + 1];
    int s2 = rp2[n], e2 = rp2[n + 1];
    int s3 = rp3[n], e3 = rp3[n + 1];
    int c0 = e0 - s0; c1 = e1 - s1; c2 = e2 - s2; c3 = e3 - s3;
    total = c0 + c1 + c2 + c3;
    addr = ((b * 4 + 0) << LOG2QE) + s0; rem = c0;
    b1 = ((b * 4 + 1) << LOG2QE) + s1;
    b2 = ((b * 4 + 2) << LOG2QE) + s2;
    b3 = ((b * 4 + 3) << LOG2QE) + s3;
    while (rem <= 0 && stage < 3) {
      ++stage;
      addr = (stage == 1) ? b1 : (stage == 2) ? b2 : b3;
      rem  = (stage == 1) ? c1 : (stage == 2) ? c2 : c3;
    }
  }

#define ADV() do { ++addr; --rem;                                   \
    while (rem <= 0 && stage < 3) { ++stage;                        \
      addr = (stage == 1) ? b1 : (stage == 2) ? b2 : b3;            \
      rem  = (stage == 1) ? c1 : (stage == 2) ? c2 : c3; } } while (0)
#define HW_COS(d, s) asm("v_cos_f32 %0, %1" : "=v"(d) : "v"(s))
#define HW_EXP2(d, s) asm("v_exp_f32 %0, %1" : "=v"(d) : "v"(s))

  float s0v = 0.f, s1v = 0.f, a00 = 0.f, a01 = 0.f, a10 = 0.f, a11 = 0.f;

  // depth-4 prologue; junk prefetch past segment ends stays inside the
  // sorted8/row_ptr ws region (valid memory) and never reaches accumulators.
  int2 r0 = sorted8[addr]; ADV();
  int2 r1 = sorted8[addr]; ADV();
  int2 r2 = sorted8[addr]; ADV();
  int2 r3 = sorted8[addr]; ADV();
  float4 hsN = lh[r0.x & (N - 1)];

  for (int it = 0; it < total; ++it) {
    int2 cur = r0;
    float4 hs = hsN;
    r0 = r1; r1 = r2; r2 = r3;
    r3 = sorted8[addr]; ADV();
    hsN = lh[r0.x & (N - 1)];  // gather 1 iteration ahead

    float dt = __int_as_float(cur.y);
    float ph0, ph1, ph2, ph3;
    HW_COS(ph0, dt * twf2[0] + tbf2[0]);
    HW_COS(ph1, dt * twf2[1] + tbf2[1]);
    HW_COS(ph2, dt * twf2[2] + tbf2[2]);
    HW_COS(ph3, dt * twf2[3] + tbf2[3]);

    float l0 = hs.x * wq[0] + hs.y * wq[1] + hs.z * wq[2]  + hs.w * wq[3]
             + ph0 * wq[8] + ph1 * wq[9] + ph2 * wq[10] + ph3 * wq[11];
    float l1 = hs.x * wq[4] + hs.y * wq[5] + hs.z * wq[6]  + hs.w * wq[7]
             + ph0 * wq[12] + ph1 * wq[13] + ph2 * wq[14] + ph3 * wq[15];

    float p0, p1;
    HW_EXP2(p0, l0);
    HW_EXP2(p1, l1);

    float v0 = hs.x * wvh[0] + hs.y * wvh[4] + hs.z * wvh[8]  + hs.w * wvh[12]
             + ph0 * wvp[0] + ph1 * wvp[4] + ph2 * wvp[8]  + ph3 * wvp[12];
    float v1 = hs.x * wvh[1] + hs.y * wvh[5] + hs.z * wvh[9]  + hs.w * wvh[13]
             + ph0 * wvp[1] + ph1 * wvp[5] + ph2 * wvp[9]  + ph3 * wvp[13];
    float v2 = hs.x * wvh[2] + hs.y * wvh[6] + hs.z * wvh[10] + hs.w * wvh[14]
             + ph0 * wvp[2] + ph1 * wvp[6] + ph2 * wvp[10] + ph3 * wvp[14];
    float v3 = hs.x * wvh[3] + hs.y * wvh[7] + hs.z * wvh[11] + hs.w * wvh[15]
             + ph0 * wvp[3] + ph1 * wvp[7] + ph2 * wvp[11] + ph3 * wvp[15];

    s0v += p0; a00 += p0 * v0; a01 += p0 * v1;
    s1v += p1; a10 += p1 * v2; a11 += p1 * v3;
  }
#undef ADV
#undef HW_COS
#undef HW_EXP2

  float den0 = (s0v == 0.f) ? 1.f : s0v;
  float den1 = (s1v == 0.f) ? 1.f : s1v;
  float at0 = a00 / den0, at1 = a01 / den0, at2 = a10 / den1, at3 = a11 / den1;

  float wof[16], bof[4];
#pragma unroll
  for (int j = 0; j < 16; j++) wof[j] = Wo[j];
#pragma unroll
  for (int j = 0; j < 4; j++) bof[j] = bo[j];

  float4 hn = lh[n];
  float o0 = bof[0] + at0 * wof[0] + at1 * wof[4] + at2 * wof[8]  + at3 * wof[12];
  float o1 = bof[1] + at0 * wof[1] + at1 * wof[5] + at2 * wof[9]  + at3 * wof[13];
  float o2 = bof[2] + at0 * wof[2] + at1 * wof[6] + at2 * wof[10] + at3 * wof[14];
  float o3 = bof[3] + at0 * wof[3] + at1 * wof[7] + at2 * wof[11] + at3 * wof[15];
  h_out[(((size_t)b) << LOG2N) + n] =
      make_float4(fmaxf(hn.x + o0, 0.f), fmaxf(hn.y + o1, 0.f),
                  fmaxf(hn.z + o2, 0.f), fmaxf(hn.w + o3, 0.f));
}

__global__ void final_kernel(const float4* __restrict__ h,
                             const int* __restrict__ src_index, const int* __restrict__ dst_index,
                             const float* __restrict__ timestamp,
                             const float* __restrict__ tw,
                             const float* __restrict__ tb,
                             const float* __restrict__ W_lin,
                             const float* __restrict__ b_lin,
                             float* __restrict__ out) {
  int b = threadIdx.x;
  if (b >= B) return;
  float4 sx = h[(((size_t)b) << LOG2N) + src_index[b]];
  float4 dx = h[(((size_t)b) << LOG2N) + dst_index[b]];
  float ts = timestamp[b];
  float f[12];
  f[0] = sx.x; f[1] = sx.y; f[2] = sx.z; f[3] = sx.w;
  f[4] = dx.x; f[5] = dx.y; f[6] = dx.z; f[7] = dx.w;
#pragma unroll
  for (int j = 0; j < 4; j++) f[8 + j] = __cosf(ts * tw[j] + tb[j]);
#pragma unroll
  for (int c = 0; c < 2; c++) {
    float o = b_lin[c];
#pragma unroll
    for (int j = 0; j < 12; j++) o += f[j] * W_lin[j * 2 + c];
    out[b * 2 + c] = o;
  }
}

}  // namespace

extern "C" void kernel_launch(void* const* d_in, const int* in_sizes, int n_in,
                              void* d_out, int out_size, void* d_ws, size_t ws_size,
                              hipStream_t stream) {
  (void)in_sizes; (void)n_in; (void)out_size; (void)ws_size;
  const float* x         = (const float*)d_in[0];
  const int*   edge_idx  = (const int*)d_in[1];
  const float* edge_time = (const float*)d_in[2];
  const float* timestamp = (const float*)d_in[3];
  const int*   src_index = (const int*)d_in[4];
  const int*   dst_index = (const int*)d_in[5];
  const float* time_w    = (const float*)d_in[6];
  const float* time_b    = (const float*)d_in[7];
  const float* Wq        = (const float*)d_in[8];
  const float* Wk        = (const float*)d_in[9];
  const float* Wv        = (const float*)d_in[10];
  const float* Wo        = (const float*)d_in[11];
  const float* bo        = (const float*)d_in[12];
  const float* W_lin     = (const float*)d_in[13];
  const float* b_lin     = (const float*)d_in[14];

  char* ws = (char*)d_ws;
  float4* h0      = (float4*)(ws + OFF_H0);
  float4* h1      = (float4*)(ws + OFF_H1);
  int2*   sorted8 = (int2*)(ws + OFF_S8);
  int*    row_ptr = (int*)(ws + OFF_RP);
  int*    perm    = (int*)(ws + OFF_PM);

  sort_kernel<<<4 * B, 1024, 0, stream>>>(edge_idx, edge_time, timestamp, sorted8, row_ptr);

  perm_kernel<<<B, 256, 0, stream>>>(row_ptr, perm);

  layer_kernel<<<2 * B, 1024, 0, stream>>>((const float4*)x, h1, row_ptr, sorted8, perm,
                                           time_w, time_b,
                                           Wq + 0 * 16, Wk + 0 * 32, Wv + 0 * 32,
                                           Wo + 0 * 16, bo + 0 * 4);
  layer_kernel<<<2 * B, 1024, 0, stream>>>(h1, h0, row_ptr, sorted8, perm,
                                           time_w, time_b,
                                           Wq + 1 * 16, Wk + 1 * 32, Wv + 1 * 32,
                                           Wo + 1 * 16, bo + 1 * 4);

  final_kernel<<<1, 128, 0, stream>>>(h0, src_index, dst_index, timestamp, time_w, time_b,
                                      W_lin, b_lin, (float*)d_out);
}

// Round 10
// 175.001 us; speedup vs baseline: 2.1906x; 1.1041x over previous
//
#include <hip/hip_runtime.h>

namespace {

constexpr int B = 128, N = 2048, E = 32768;
constexpr int LOG2N = 11, LOG2E = 15;
constexpr int QE = E / 4;          // edges per quarter block = 8192
constexpr int LOG2QE = 13;

// ws layout (bytes) — identical to R3 (proven to fit)
constexpr size_t OFF_H0 = 0;                     // B*N float4 = 4 MB
constexpr size_t OFF_H1 = 4u * 1024 * 1024;      // B*N float4 = 4 MB
constexpr size_t OFF_S8 = 8u * 1024 * 1024;      // B*4 quarters * QE int2 = 32 MB
constexpr size_t OFF_RP = 40u * 1024 * 1024;     // B*4*(N+1) int ~ 4.2 MB

// One block per (batch, quarter). Builds a per-quarter CSR of (src, dt)
// records entirely in LDS, then streams it out coalesced. (R3-verbatim.)
__global__ __launch_bounds__(1024) void sort_kernel(const int* __restrict__ edge_index,
                                                    const float* __restrict__ edge_time,
                                                    const float* __restrict__ timestamp,
                                                    int2* __restrict__ sorted8,
                                                    int* __restrict__ row_ptr) {
  __shared__ int  cnt[N];        // 8 KB: counts -> cursors
  __shared__ int  wsum[16];
  __shared__ int2 rec[QE];       // 64 KB: local CSR records
  int blk = blockIdx.x, b = blk >> 2, q = blk & 3, t = threadIdx.x;

  cnt[t] = 0; cnt[t + 1024] = 0;
  __syncthreads();

  const int* src_arr = edge_index + (((size_t)(2 * b)) << LOG2E) + q * QE;
  const int* dst_arr = edge_index + (((size_t)(2 * b + 1)) << LOG2E) + q * QE;
  const float* et    = edge_time + (((size_t)b) << LOG2E) + q * QE;
  float ts = timestamp[b];

  // single-pass edge staging into registers (indices all compile-time)
  int srcv[8], dstv[8]; float dtv[8];
#pragma unroll
  for (int k = 0; k < 8; ++k) {
    int e = t + k * 1024;
    srcv[k] = src_arr[e];
    dstv[k] = dst_arr[e];
    dtv[k]  = ts - et[e];
  }

  // hist
#pragma unroll
  for (int k = 0; k < 8; ++k) atomicAdd(&cnt[dstv[k]], 1);
  __syncthreads();

  // exclusive scan of 2048 counts: wave shuffle + 16-partial scan
  int i0 = 2 * t, i1 = 2 * t + 1;
  int l0 = cnt[i0], l1 = cnt[i1];
  int sum = l0 + l1;
  int lane = t & 63, wid = t >> 6;
  int incl = sum;
#pragma unroll
  for (int d = 1; d < 64; d <<= 1) {
    int v = __shfl_up(incl, d, 64);
    if (lane >= d) incl += v;
  }
  if (lane == 63) wsum[wid] = incl;
  __syncthreads();
  if (t < 16) {
    int v = wsum[t];
    int inc = v;
#pragma unroll
    for (int d = 1; d < 16; d <<= 1) {
      int u = __shfl_up(inc, d, 16);
      if (t >= d) inc += u;
    }
    wsum[t] = inc - v;  // exclusive wave offset
  }
  __syncthreads();
  int run = wsum[wid] + (incl - sum);
  int run2 = run + l0;
  int* rp = row_ptr + (size_t)blk * (N + 1);
  rp[i0] = run;
  rp[i1] = run2;
  if (t == 1023) rp[N] = QE;
  cnt[i0] = run;   // becomes cursor
  cnt[i1] = run2;
  __syncthreads();

  // scatter into LDS CSR straight from registers
#pragma unroll
  for (int k = 0; k < 8; ++k) {
    int pos = atomicAdd(&cnt[dstv[k]], 1);
    rec[pos] = make_int2(srcv[k], __float_as_int(dtv[k]));
  }
  __syncthreads();

  // coalesced stream-out (int4 = 2 records)
  const int4* rec4 = (const int4*)rec;
  int4* out4 = (int4*)(sorted8 + (((size_t)blk) << LOG2QE));
#pragma unroll
  for (int i = t; i < QE / 2; i += 1024) out4[i] = rec4[i];
}

// R14 split-K layer. Grid 4B x 1024: block (b, nq) owns nodes
// [512nq, 512nq+512). Thread t: node = nq*512 + (t&511); kpair = t>>9
// walks quarters {2*kpair, 2*kpair+1}. 512 blocks on 256 CUs -> 2 blocks/CU
// = 8 waves/SIMD (2x R3's TLP), wave-max trip ~15.5 vs 27 (1.74x less
// divergence), segment contiguity preserved (R9 lesson). Partner partials
// (pure sums -- no online max, R7-validated) merge via LDS; kpair=0 runs
// the epilogue. Body/numerics R3-verbatim.
__global__ __launch_bounds__(1024, 4) void layer_kernel(const float4* __restrict__ h_in,
                                                        float4* __restrict__ h_out,
                                                        const int* __restrict__ row_ptr,
                                                        const int2* __restrict__ sorted8,
                                                        const float* __restrict__ tw,
                                                        const float* __restrict__ tb,
                                                        const float* __restrict__ Wq,
                                                        const float* __restrict__ Wk,
                                                        const float* __restrict__ Wv,
                                                        const float* __restrict__ Wo,
                                                        const float* __restrict__ bo) {
  __shared__ float4 lh[N];          // 32 KB
  __shared__ float  mrg[512 * 7];   // 14 KB, stride 7 (gcd(7,32)=1 -> spread banks)
  int blk = blockIdx.x, b = blk >> 2, nq = blk & 3, t = threadIdx.x;
  int nloc = t & 511, kpair = t >> 9;

  const float4* hb = h_in + (((size_t)b) << LOG2N);
  lh[t] = hb[t];
  lh[t + 1024] = hb[t + 1024];

  constexpr float INV2PI = 0.15915494309189535f;
  constexpr float QSCALE = 0.70710678118654752f * 1.4426950408889634f;  // rs2*log2e
  float twf2[4], tbf2[4], wq[16], wkh[16], wkp[16], wvh[16], wvp[16];
#pragma unroll
  for (int j = 0; j < 4; j++) { twf2[j] = tw[j] * INV2PI; tbf2[j] = tb[j] * INV2PI; }
#pragma unroll
  for (int j = 0; j < 16; j++) wq[j] = Wq[j];
#pragma unroll
  for (int j = 0; j < 16; j++) { wkh[j] = Wk[j]; wkp[j] = Wk[16 + j]; }
#pragma unroll
  for (int j = 0; j < 16; j++) { wvh[j] = Wv[j]; wvp[j] = Wv[16 + j]; }
  __syncthreads();

  int n = nq * 512 + nloc;
  {
    float4 hn = lh[n];
    float q0 = (hn.x * wq[0] + hn.y * wq[4] + hn.z * wq[8]  + hn.w * wq[12]) * QSCALE;
    float q1 = (hn.x * wq[1] + hn.y * wq[5] + hn.z * wq[9]  + hn.w * wq[13]) * QSCALE;
    float q2 = (hn.x * wq[2] + hn.y * wq[6] + hn.z * wq[10] + hn.w * wq[14]) * QSCALE;
    float q3 = (hn.x * wq[3] + hn.y * wq[7] + hn.z * wq[11] + hn.w * wq[15]) * QSCALE;
#pragma unroll
    for (int i = 0; i < 4; i++) {
      wq[i]      = q0 * wkh[i * 4 + 0] + q1 * wkh[i * 4 + 1];  // wH0
      wq[4 + i]  = q2 * wkh[i * 4 + 2] + q3 * wkh[i * 4 + 3];  // wH1
      wq[8 + i]  = q0 * wkp[i * 4 + 0] + q1 * wkp[i * 4 + 1];  // wA
      wq[12 + i] = q2 * wkp[i * 4 + 2] + q3 * wkp[i * 4 + 3];  // wB
    }
  }

  // cursor over this thread's TWO quarter segments (contiguous runs)
  int qA = b * 4 + 2 * kpair, qB = qA + 1;
  int addr, rem, total, addrB, cB;
  {
    const int* rpA = row_ptr + (size_t)qA * (N + 1);
    const int* rpB = row_ptr + (size_t)qB * (N + 1);
    int sA = rpA[n], cA = rpA[n + 1] - sA;
    int sB = rpB[n]; cB = rpB[n + 1] - sB;
    total = cA + cB;
    addr  = (qA << LOG2QE) + sA; rem = cA;
    addrB = (qB << LOG2QE) + sB;
    if (rem <= 0) { addr = addrB; rem = cB; cB = -1; }  // cB=-1 marks B active
  }

#define ADV() do { ++addr; --rem;                                     \
    if (rem <= 0 && cB >= 0) { addr = addrB; rem = cB; cB = -1; } } while (0)
#define HW_COS(d, s) asm("v_cos_f32 %0, %1" : "=v"(d) : "v"(s))
#define HW_EXP2(d, s) asm("v_exp_f32 %0, %1" : "=v"(d) : "v"(s))

  float s0v = 0.f, s1v = 0.f, a00 = 0.f, a01 = 0.f, a10 = 0.f, a11 = 0.f;

  // depth-4 prologue; junk prefetch past segment ends stays inside the
  // sorted8/row_ptr ws region (valid memory) and never reaches accumulators.
  int2 r0 = sorted8[addr]; ADV();
  int2 r1 = sorted8[addr]; ADV();
  int2 r2 = sorted8[addr]; ADV();
  int2 r3 = sorted8[addr]; ADV();
  float4 hsN = lh[r0.x & (N - 1)];

  for (int it = 0; it < total; ++it) {
    int2 cur = r0;
    float4 hs = hsN;
    r0 = r1; r1 = r2; r2 = r3;
    r3 = sorted8[addr]; ADV();
    hsN = lh[r0.x & (N - 1)];  // gather 1 iteration ahead

    float dt = __int_as_float(cur.y);
    float ph0, ph1, ph2, ph3;
    HW_COS(ph0, dt * twf2[0] + tbf2[0]);
    HW_COS(ph1, dt * twf2[1] + tbf2[1]);
    HW_COS(ph2, dt * twf2[2] + tbf2[2]);
    HW_COS(ph3, dt * twf2[3] + tbf2[3]);

    float l0 = hs.x * wq[0] + hs.y * wq[1] + hs.z * wq[2]  + hs.w * wq[3]
             + ph0 * wq[8] + ph1 * wq[9] + ph2 * wq[10] + ph3 * wq[11];
    float l1 = hs.x * wq[4] + hs.y * wq[5] + hs.z * wq[6]  + hs.w * wq[7]
             + ph0 * wq[12] + ph1 * wq[13] + ph2 * wq[14] + ph3 * wq[15];

    float p0, p1;
    HW_EXP2(p0, l0);
    HW_EXP2(p1, l1);

    float v0 = hs.x * wvh[0] + hs.y * wvh[4] + hs.z * wvh[8]  + hs.w * wvh[12]
             + ph0 * wvp[0] + ph1 * wvp[4] + ph2 * wvp[8]  + ph3 * wvp[12];
    float v1 = hs.x * wvh[1] + hs.y * wvh[5] + hs.z * wvh[9]  + hs.w * wvh[13]
             + ph0 * wvp[1] + ph1 * wvp[5] + ph2 * wvp[9]  + ph3 * wvp[13];
    float v2 = hs.x * wvh[2] + hs.y * wvh[6] + hs.z * wvh[10] + hs.w * wvh[14]
             + ph0 * wvp[2] + ph1 * wvp[6] + ph2 * wvp[10] + ph3 * wvp[14];
    float v3 = hs.x * wvh[3] + hs.y * wvh[7] + hs.z * wvh[11] + hs.w * wvh[15]
             + ph0 * wvp[3] + ph1 * wvp[7] + ph2 * wvp[11] + ph3 * wvp[15];

    s0v += p0; a00 += p0 * v0; a01 += p0 * v1;
    s1v += p1; a10 += p1 * v2; a11 += p1 * v3;
  }
#undef ADV
#undef HW_COS
#undef HW_EXP2

  // split-K merge: kpair=1 publishes its 6 sums; kpair=0 combines + epilogue
  if (kpair) {
    int base = nloc * 7;
    mrg[base + 0] = s0v; mrg[base + 1] = s1v;
    mrg[base + 2] = a00; mrg[base + 3] = a01;
    mrg[base + 4] = a10; mrg[base + 5] = a11;
  }
  __syncthreads();
  if (!kpair) {
    int base = nloc * 7;
    s0v += mrg[base + 0]; s1v += mrg[base + 1];
    a00 += mrg[base + 2]; a01 += mrg[base + 3];
    a10 += mrg[base + 4]; a11 += mrg[base + 5];

    float den0 = (s0v == 0.f) ? 1.f : s0v;
    float den1 = (s1v == 0.f) ? 1.f : s1v;
    float at0 = a00 / den0, at1 = a01 / den0, at2 = a10 / den1, at3 = a11 / den1;

    float wof[16], bof[4];
#pragma unroll
    for (int j = 0; j < 16; j++) wof[j] = Wo[j];
#pragma unroll
    for (int j = 0; j < 4; j++) bof[j] = bo[j];

    float4 hn = lh[n];
    float o0 = bof[0] + at0 * wof[0] + at1 * wof[4] + at2 * wof[8]  + at3 * wof[12];
    float o1 = bof[1] + at0 * wof[1] + at1 * wof[5] + at2 * wof[9]  + at3 * wof[13];
    float o2 = bof[2] + at0 * wof[2] + at1 * wof[6] + at2 * wof[10] + at3 * wof[14];
    float o3 = bof[3] + at0 * wof[3] + at1 * wof[7] + at2 * wof[11] + at3 * wof[15];
    h_out[(((size_t)b) << LOG2N) + n] =
        make_float4(fmaxf(hn.x + o0, 0.f), fmaxf(hn.y + o1, 0.f),
                    fmaxf(hn.z + o2, 0.f), fmaxf(hn.w + o3, 0.f));
  }
}

__global__ void final_kernel(const float4* __restrict__ h,
                             const int* __restrict__ src_index, const int* __restrict__ dst_index,
                             const float* __restrict__ timestamp,
                             const float* __restrict__ tw,
                             const float* __restrict__ tb,
                             const float* __restrict__ W_lin,
                             const float* __restrict__ b_lin,
                             float* __restrict__ out) {
  int b = threadIdx.x;
  if (b >= B) return;
  float4 sx = h[(((size_t)b) << LOG2N) + src_index[b]];
  float4 dx = h[(((size_t)b) << LOG2N) + dst_index[b]];
  float ts = timestamp[b];
  float f[12];
  f[0] = sx.x; f[1] = sx.y; f[2] = sx.z; f[3] = sx.w;
  f[4] = dx.x; f[5] = dx.y; f[6] = dx.z; f[7] = dx.w;
#pragma unroll
  for (int j = 0; j < 4; j++) f[8 + j] = __cosf(ts * tw[j] + tb[j]);
#pragma unroll
  for (int c = 0; c < 2; c++) {
    float o = b_lin[c];
#pragma unroll
    for (int j = 0; j < 12; j++) o += f[j] * W_lin[j * 2 + c];
    out[b * 2 + c] = o;
  }
}

}  // namespace

extern "C" void kernel_launch(void* const* d_in, const int* in_sizes, int n_in,
                              void* d_out, int out_size, void* d_ws, size_t ws_size,
                              hipStream_t stream) {
  (void)in_sizes; (void)n_in; (void)out_size; (void)ws_size;
  const float* x         = (const float*)d_in[0];
  const int*   edge_idx  = (const int*)d_in[1];
  const float* edge_time = (const float*)d_in[2];
  const float* timestamp = (const float*)d_in[3];
  const int*   src_index = (const int*)d_in[4];
  const int*   dst_index = (const int*)d_in[5];
  const float* time_w    = (const float*)d_in[6];
  const float* time_b    = (const float*)d_in[7];
  const float* Wq        = (const float*)d_in[8];
  const float* Wk        = (const float*)d_in[9];
  const float* Wv        = (const float*)d_in[10];
  const float* Wo        = (const float*)d_in[11];
  const float* bo        = (const float*)d_in[12];
  const float* W_lin     = (const float*)d_in[13];
  const float* b_lin     = (const float*)d_in[14];

  char* ws = (char*)d_ws;
  float4* h0      = (float4*)(ws + OFF_H0);
  float4* h1      = (float4*)(ws + OFF_H1);
  int2*   sorted8 = (int2*)(ws + OFF_S8);
  int*    row_ptr = (int*)(ws + OFF_RP);

  sort_kernel<<<4 * B, 1024, 0, stream>>>(edge_idx, edge_time, timestamp, sorted8, row_ptr);

  layer_kernel<<<4 * B, 1024, 0, stream>>>((const float4*)x, h1, row_ptr, sorted8,
                                           time_w, time_b,
                                           Wq + 0 * 16, Wk + 0 * 32, Wv + 0 * 32,
                                           Wo + 0 * 16, bo + 0 * 4);
  layer_kernel<<<4 * B, 1024, 0, stream>>>(h1, h0, row_ptr, sorted8,
                                           time_w, time_b,
                                           Wq + 1 * 16, Wk + 1 * 32, Wv + 1 * 32,
                                           Wo + 1 * 16, bo + 1 * 4);

  final_kernel<<<1, 128, 0, stream>>>(h0, src_index, dst_index, timestamp, time_w, time_b,
                                      W_lin, b_lin, (float*)d_out);
}

// Round 11
// 168.413 us; speedup vs baseline: 2.2763x; 1.0391x over previous
//
#include <hip/hip_runtime.h>

namespace {

constexpr int B = 128, N = 2048, E = 32768;
constexpr int LOG2N = 11, LOG2E = 15;
constexpr int QE = E / 4;          // edges per quarter block = 8192
constexpr int LOG2QE = 13;

// ws layout (bytes) — identical to R3 (proven to fit)
constexpr size_t OFF_H0 = 0;                     // B*N float4 = 4 MB
constexpr size_t OFF_H1 = 4u * 1024 * 1024;      // B*N float4 = 4 MB
constexpr size_t OFF_S8 = 8u * 1024 * 1024;      // B*4 quarters * QE int2 = 32 MB
constexpr size_t OFF_RP = 40u * 1024 * 1024;     // B*4*(N+1) int ~ 4.2 MB

// R15: XCD colocation. XCD = blockIdx % 8 (round-robin dispatch). Grid
// indices are remapped so ALL blocks touching batch b (4 sort quarters,
// 2 layer halves) land on XCD b%8: bid = q*128 + b / half*128 + b
// (128 = 0 mod 8). Batch b's CSR (256 KB) + h (32 KB) then live in ONE
// XCD's L2 (16 batches x 288 KB = 4.6 MB/XCD), turning the layer's
// record loads from remote-L2/L3 (~500-900 cyc, under-covered by the
// depth-4 pipeline) into local-L2 hits (~200 cyc). Pure index remap;
// work and numerics are R3-verbatim.

// One block per (quarter, batch). Builds a per-quarter CSR of (src, dt)
// records entirely in LDS, then streams it out coalesced.
__global__ __launch_bounds__(1024) void sort_kernel(const int* __restrict__ edge_index,
                                                    const float* __restrict__ edge_time,
                                                    const float* __restrict__ timestamp,
                                                    int2* __restrict__ sorted8,
                                                    int* __restrict__ row_ptr) {
  __shared__ int  cnt[N];        // 8 KB: counts -> cursors
  __shared__ int  wsum[16];
  __shared__ int2 rec[QE];       // 64 KB: local CSR records
  int b = blockIdx.x & 127, q = blockIdx.x >> 7, t = threadIdx.x;  // XCD = b%8
  int blk = b * 4 + q;           // CSR block index (layout unchanged)

  cnt[t] = 0; cnt[t + 1024] = 0;
  __syncthreads();

  const int* src_arr = edge_index + (((size_t)(2 * b)) << LOG2E) + q * QE;
  const int* dst_arr = edge_index + (((size_t)(2 * b + 1)) << LOG2E) + q * QE;
  const float* et    = edge_time + (((size_t)b) << LOG2E) + q * QE;
  float ts = timestamp[b];

  // single-pass edge staging into registers (indices all compile-time)
  int srcv[8], dstv[8]; float dtv[8];
#pragma unroll
  for (int k = 0; k < 8; ++k) {
    int e = t + k * 1024;
    srcv[k] = src_arr[e];
    dstv[k] = dst_arr[e];
    dtv[k]  = ts - et[e];
  }

  // hist
#pragma unroll
  for (int k = 0; k < 8; ++k) atomicAdd(&cnt[dstv[k]], 1);
  __syncthreads();

  // exclusive scan of 2048 counts: wave shuffle + 16-partial scan
  int i0 = 2 * t, i1 = 2 * t + 1;
  int l0 = cnt[i0], l1 = cnt[i1];
  int sum = l0 + l1;
  int lane = t & 63, wid = t >> 6;
  int incl = sum;
#pragma unroll
  for (int d = 1; d < 64; d <<= 1) {
    int v = __shfl_up(incl, d, 64);
    if (lane >= d) incl += v;
  }
  if (lane == 63) wsum[wid] = incl;
  __syncthreads();
  if (t < 16) {
    int v = wsum[t];
    int inc = v;
#pragma unroll
    for (int d = 1; d < 16; d <<= 1) {
      int u = __shfl_up(inc, d, 16);
      if (t >= d) inc += u;
    }
    wsum[t] = inc - v;  // exclusive wave offset
  }
  __syncthreads();
  int run = wsum[wid] + (incl - sum);
  int run2 = run + l0;
  int* rp = row_ptr + (size_t)blk * (N + 1);
  rp[i0] = run;
  rp[i1] = run2;
  if (t == 1023) rp[N] = QE;
  cnt[i0] = run;   // becomes cursor
  cnt[i1] = run2;
  __syncthreads();

  // scatter into LDS CSR straight from registers
#pragma unroll
  for (int k = 0; k < 8; ++k) {
    int pos = atomicAdd(&cnt[dstv[k]], 1);
    rec[pos] = make_int2(srcv[k], __float_as_int(dtv[k]));
  }
  __syncthreads();

  // coalesced stream-out (int4 = 2 records)
  const int4* rec4 = (const int4*)rec;
  int4* out4 = (int4*)(sorted8 + (((size_t)blk) << LOG2QE));
#pragma unroll
  for (int i = t; i < QE / 2; i += 1024) out4[i] = rec4[i];
}

// R3 layer body verbatim; only the (b, half) <- blockIdx mapping changed
// for XCD colocation.
__global__ __launch_bounds__(1024) void layer_kernel(const float4* __restrict__ h_in,
                                                     float4* __restrict__ h_out,
                                                     const int* __restrict__ row_ptr,
                                                     const int2* __restrict__ sorted8,
                                                     const float* __restrict__ tw,
                                                     const float* __restrict__ tb,
                                                     const float* __restrict__ Wq,
                                                     const float* __restrict__ Wk,
                                                     const float* __restrict__ Wv,
                                                     const float* __restrict__ Wo,
                                                     const float* __restrict__ bo) {
  __shared__ float4 lh[N];  // 32 KB
  int b = blockIdx.x & 127, half = blockIdx.x >> 7, t = threadIdx.x;  // XCD = b%8

  const float4* hb = h_in + (((size_t)b) << LOG2N);
  lh[t] = hb[t];
  lh[t + 1024] = hb[t + 1024];

  constexpr float INV2PI = 0.15915494309189535f;
  constexpr float QSCALE = 0.70710678118654752f * 1.4426950408889634f;  // rs2*log2e
  float twf2[4], tbf2[4], wq[16], wkh[16], wkp[16], wvh[16], wvp[16];
#pragma unroll
  for (int j = 0; j < 4; j++) { twf2[j] = tw[j] * INV2PI; tbf2[j] = tb[j] * INV2PI; }
#pragma unroll
  for (int j = 0; j < 16; j++) wq[j] = Wq[j];
#pragma unroll
  for (int j = 0; j < 16; j++) { wkh[j] = Wk[j]; wkp[j] = Wk[16 + j]; }
#pragma unroll
  for (int j = 0; j < 16; j++) { wvh[j] = Wv[j]; wvp[j] = Wv[16 + j]; }
  __syncthreads();

  int n = half * 1024 + t;
  {
    float4 hn = lh[n];
    float q0 = (hn.x * wq[0] + hn.y * wq[4] + hn.z * wq[8]  + hn.w * wq[12]) * QSCALE;
    float q1 = (hn.x * wq[1] + hn.y * wq[5] + hn.z * wq[9]  + hn.w * wq[13]) * QSCALE;
    float q2 = (hn.x * wq[2] + hn.y * wq[6] + hn.z * wq[10] + hn.w * wq[14]) * QSCALE;
    float q3 = (hn.x * wq[3] + hn.y * wq[7] + hn.z * wq[11] + hn.w * wq[15]) * QSCALE;
#pragma unroll
    for (int i = 0; i < 4; i++) {
      wq[i]      = q0 * wkh[i * 4 + 0] + q1 * wkh[i * 4 + 1];  // wH0
      wq[4 + i]  = q2 * wkh[i * 4 + 2] + q3 * wkh[i * 4 + 3];  // wH1
      wq[8 + i]  = q0 * wkp[i * 4 + 0] + q1 * wkp[i * 4 + 1];  // wA
      wq[12 + i] = q2 * wkp[i * 4 + 2] + q3 * wkp[i * 4 + 3];  // wB
    }
  }

  // flattened cursor over the 4 quarter CSR segments (absolute record index)
  int stage = 0, addr, rem, total;
  int b1, b2, b3, c1, c2, c3;
  {
    const int* rp0 = row_ptr + (size_t)(b * 4 + 0) * (N + 1);
    const int* rp1 = row_ptr + (size_t)(b * 4 + 1) * (N + 1);
    const int* rp2 = row_ptr + (size_t)(b * 4 + 2) * (N + 1);
    const int* rp3 = row_ptr + (size_t)(b * 4 + 3) * (N + 1);
    int s0 = rp0[n], e0 = rp0[n + 1];
    int s1 = rp1[n], e1 = rp1[n + 1];
    int s2 = rp2[n], e2 = rp2[n + 1];
    int s3 = rp3[n], e3 = rp3[n + 1];
    int c0 = e0 - s0; c1 = e1 - s1; c2 = e2 - s2; c3 = e3 - s3;
    total = c0 + c1 + c2 + c3;
    addr = ((b * 4 + 0) << LOG2QE) + s0; rem = c0;
    b1 = ((b * 4 + 1) << LOG2QE) + s1;
    b2 = ((b * 4 + 2) << LOG2QE) + s2;
    b3 = ((b * 4 + 3) << LOG2QE) + s3;
    while (rem <= 0 && stage < 3) {
      ++stage;
      addr = (stage == 1) ? b1 : (stage == 2) ? b2 : b3;
      rem  = (stage == 1) ? c1 : (stage == 2) ? c2 : c3;
    }
  }

#define ADV() do { ++addr; --rem;                                   \
    while (rem <= 0 && stage < 3) { ++stage;                        \
      addr = (stage == 1) ? b1 : (stage == 2) ? b2 : b3;            \
      rem  = (stage == 1) ? c1 : (stage == 2) ? c2 : c3; } } while (0)
#define HW_COS(d, s) asm("v_cos_f32 %0, %1" : "=v"(d) : "v"(s))
#define HW_EXP2(d, s) asm("v_exp_f32 %0, %1" : "=v"(d) : "v"(s))

  float s0v = 0.f, s1v = 0.f, a00 = 0.f, a01 = 0.f, a10 = 0.f, a11 = 0.f;

  // depth-4 prologue; junk prefetch past segment ends stays inside the
  // sorted8/row_ptr ws region (valid memory) and never reaches accumulators.
  int2 r0 = sorted8[addr]; ADV();
  int2 r1 = sorted8[addr]; ADV();
  int2 r2 = sorted8[addr]; ADV();
  int2 r3 = sorted8[addr]; ADV();
  float4 hsN = lh[r0.x & (N - 1)];

  for (int it = 0; it < total; ++it) {
    int2 cur = r0;
    float4 hs = hsN;
    r0 = r1; r1 = r2; r2 = r3;
    r3 = sorted8[addr]; ADV();
    hsN = lh[r0.x & (N - 1)];  // gather 1 iteration ahead

    float dt = __int_as_float(cur.y);
    float ph0, ph1, ph2, ph3;
    HW_COS(ph0, dt * twf2[0] + tbf2[0]);
    HW_COS(ph1, dt * twf2[1] + tbf2[1]);
    HW_COS(ph2, dt * twf2[2] + tbf2[2]);
    HW_COS(ph3, dt * twf2[3] + tbf2[3]);

    float l0 = hs.x * wq[0] + hs.y * wq[1] + hs.z * wq[2]  + hs.w * wq[3]
             + ph0 * wq[8] + ph1 * wq[9] + ph2 * wq[10] + ph3 * wq[11];
    float l1 = hs.x * wq[4] + hs.y * wq[5] + hs.z * wq[6]  + hs.w * wq[7]
             + ph0 * wq[12] + ph1 * wq[13] + ph2 * wq[14] + ph3 * wq[15];

    float p0, p1;
    HW_EXP2(p0, l0);
    HW_EXP2(p1, l1);

    float v0 = hs.x * wvh[0] + hs.y * wvh[4] + hs.z * wvh[8]  + hs.w * wvh[12]
             + ph0 * wvp[0] + ph1 * wvp[4] + ph2 * wvp[8]  + ph3 * wvp[12];
    float v1 = hs.x * wvh[1] + hs.y * wvh[5] + hs.z * wvh[9]  + hs.w * wvh[13]
             + ph0 * wvp[1] + ph1 * wvp[5] + ph2 * wvp[9]  + ph3 * wvp[13];
    float v2 = hs.x * wvh[2] + hs.y * wvh[6] + hs.z * wvh[10] + hs.w * wvh[14]
             + ph0 * wvp[2] + ph1 * wvp[6] + ph2 * wvp[10] + ph3 * wvp[14];
    float v3 = hs.x * wvh[3] + hs.y * wvh[7] + hs.z * wvh[11] + hs.w * wvh[15]
             + ph0 * wvp[3] + ph1 * wvp[7] + ph2 * wvp[11] + ph3 * wvp[15];

    s0v += p0; a00 += p0 * v0; a01 += p0 * v1;
    s1v += p1; a10 += p1 * v2; a11 += p1 * v3;
  }
#undef ADV
#undef HW_COS
#undef HW_EXP2

  float den0 = (s0v == 0.f) ? 1.f : s0v;
  float den1 = (s1v == 0.f) ? 1.f : s1v;
  float at0 = a00 / den0, at1 = a01 / den0, at2 = a10 / den1, at3 = a11 / den1;

  float wof[16], bof[4];
#pragma unroll
  for (int j = 0; j < 16; j++) wof[j] = Wo[j];
#pragma unroll
  for (int j = 0; j < 4; j++) bof[j] = bo[j];

  float4 hn = lh[n];
  float o0 = bof[0] + at0 * wof[0] + at1 * wof[4] + at2 * wof[8]  + at3 * wof[12];
  float o1 = bof[1] + at0 * wof[1] + at1 * wof[5] + at2 * wof[9]  + at3 * wof[13];
  float o2 = bof[2] + at0 * wof[2] + at1 * wof[6] + at2 * wof[10] + at3 * wof[14];
  float o3 = bof[3] + at0 * wof[3] + at1 * wof[7] + at2 * wof[11] + at3 * wof[15];
  h_out[(((size_t)b) << LOG2N) + n] =
      make_float4(fmaxf(hn.x + o0, 0.f), fmaxf(hn.y + o1, 0.f),
                  fmaxf(hn.z + o2, 0.f), fmaxf(hn.w + o3, 0.f));
}

__global__ void final_kernel(const float4* __restrict__ h,
                             const int* __restrict__ src_index, const int* __restrict__ dst_index,
                             const float* __restrict__ timestamp,
                             const float* __restrict__ tw,
                             const float* __restrict__ tb,
                             const float* __restrict__ W_lin,
                             const float* __restrict__ b_lin,
                             float* __restrict__ out) {
  int b = threadIdx.x;
  if (b >= B) return;
  float4 sx = h[(((size_t)b) << LOG2N) + src_index[b]];
  float4 dx = h[(((size_t)b) << LOG2N) + dst_index[b]];
  float ts = timestamp[b];
  float f[12];
  f[0] = sx.x; f[1] = sx.y; f[2] = sx.z; f[3] = sx.w;
  f[4] = dx.x; f[5] = dx.y; f[6] = dx.z; f[7] = dx.w;
#pragma unroll
  for (int j = 0; j < 4; j++) f[8 + j] = __cosf(ts * tw[j] + tb[j]);
#pragma unroll
  for (int c = 0; c < 2; c++) {
    float o = b_lin[c];
#pragma unroll
    for (int j = 0; j < 12; j++) o += f[j] * W_lin[j * 2 + c];
    out[b * 2 + c] = o;
  }
}

}  // namespace

extern "C" void kernel_launch(void* const* d_in, const int* in_sizes, int n_in,
                              void* d_out, int out_size, void* d_ws, size_t ws_size,
                              hipStream_t stream) {
  (void)in_sizes; (void)n_in; (void)out_size; (void)ws_size;
  const float* x         = (const float*)d_in[0];
  const int*   edge_idx  = (const int*)d_in[1];
  const float* edge_time = (const float*)d_in[2];
  const float* timestamp = (const float*)d_in[3];
  const int*   src_index = (const int*)d_in[4];
  const int*   dst_index = (const int*)d_in[5];
  const float* time_w    = (const float*)d_in[6];
  const float* time_b    = (const float*)d_in[7];
  const float* Wq        = (const float*)d_in[8];
  const float* Wk        = (const float*)d_in[9];
  const float* Wv        = (const float*)d_in[10];
  const float* Wo        = (const float*)d_in[11];
  const float* bo        = (const float*)d_in[12];
  const float* W_lin     = (const float*)d_in[13];
  const float* b_lin     = (const float*)d_in[14];

  char* ws = (char*)d_ws;
  float4* h0      = (float4*)(ws + OFF_H0);
  float4* h1      = (float4*)(ws + OFF_H1);
  int2*   sorted8 = (int2*)(ws + OFF_S8);
  int*    row_ptr = (int*)(ws + OFF_RP);

  sort_kernel<<<4 * B, 1024, 0, stream>>>(edge_idx, edge_time, timestamp, sorted8, row_ptr);

  layer_kernel<<<2 * B, 1024, 0, stream>>>((const float4*)x, h1, row_ptr, sorted8,
                                           time_w, time_b,
                                           Wq + 0 * 16, Wk + 0 * 32, Wv + 0 * 32,
                                           Wo + 0 * 16, bo + 0 * 4);
  layer_kernel<<<2 * B, 1024, 0, stream>>>(h1, h0, row_ptr, sorted8,
                                           time_w, time_b,
                                           Wq + 1 * 16, Wk + 1 * 32, Wv + 1 * 32,
                                           Wo + 1 * 16, bo + 1 * 4);

  final_kernel<<<1, 128, 0, stream>>>(h0, src_index, dst_index, timestamp, time_w, time_b,
                                      W_lin, b_lin, (float*)d_out);
}